// Round 7
// baseline (323.497 us; speedup 1.0000x reference)
//
#include <hip/hip_runtime.h>
#include <hip/hip_bf16.h>

#define B_  2
#define L_  2048
#define HS_ 2048
#define NH_ 16
#define NKV_ 4
#define HD_ 128
#define EPS_ 1e-6f
#define SCALE_ 0.08838834764831843f
#define LOG2E_ 1.4426950408889634f

typedef __attribute__((ext_vector_type(8))) short bf16x8;
typedef __attribute__((ext_vector_type(4))) float f32x4;

__device__ __forceinline__ f32x4 mfma16(bf16x8 a, bf16x8 b, f32x4 c) {
    return __builtin_amdgcn_mfma_f32_16x16x32_bf16(a, b, c, 0, 0, 0);
}

__device__ __forceinline__ void async_copy16(void* lds, const void* g) {
    __builtin_amdgcn_global_load_lds(
        (const __attribute__((address_space(1))) unsigned int*)g,
        (__attribute__((address_space(3))) unsigned int*)lds,
        16, 0, 0);
}

// Single-instruction RNE f32 pair -> packed bf16.
__device__ __forceinline__ unsigned cvtpk(float lo, float hi) {
    unsigned r;
    asm("v_cvt_pk_bf16_f32 %0, %1, %2" : "=v"(r) : "v"(lo), "v"(hi));
    return r;
}

// ---------------------------------------------------------------------------
// fused_prep: one launch covering hidden cvt + 4 weight transposes.
__global__ __launch_bounds__(256) void fused_prep(
    const float* __restrict__ hidden, __hip_bfloat16* __restrict__ A_h,
    const float* __restrict__ Wq, __hip_bfloat16* __restrict__ Wq_t,
    const float* __restrict__ Wk, __hip_bfloat16* __restrict__ Wk_t,
    const float* __restrict__ Wv, __hip_bfloat16* __restrict__ Wv_t,
    const float* __restrict__ Wo, __hip_bfloat16* __restrict__ Wo_t) {
    __shared__ float tile[32][33];
    int bid = blockIdx.x;
    if (bid < 8192) {
        int i = bid * 256 + threadIdx.x;
        float4 v = ((const float4*)hidden)[i];
        union { __hip_bfloat16 h[4]; short4 s; } u;
        u.h[0] = __float2bfloat16(v.x);
        u.h[1] = __float2bfloat16(v.y);
        u.h[2] = __float2bfloat16(v.z);
        u.h[3] = __float2bfloat16(v.w);
        ((short4*)A_h)[i] = u.s;
        return;
    }
    const float* src; __hip_bfloat16* dst; int N, tb;
    if (bid < 12288)      { tb = bid - 8192;  src = Wq; dst = Wq_t; N = 2048; }
    else if (bid < 13312) { tb = bid - 12288; src = Wk; dst = Wk_t; N = 512;  }
    else if (bid < 14336) { tb = bid - 13312; src = Wv; dst = Wv_t; N = 512;  }
    else                  { tb = bid - 14336; src = Wo; dst = Wo_t; N = 2048; }
    int nt = N >> 5;
    int n0 = (tb % nt) * 32, k0 = (tb / nt) * 32;
    int tx = threadIdx.x & 31, ty = threadIdx.x >> 5;
#pragma unroll
    for (int i = 0; i < 32; i += 8)
        tile[ty + i][tx] = src[(size_t)(k0 + ty + i) * N + n0 + tx];
    __syncthreads();
#pragma unroll
    for (int i = 0; i < 32; i += 8)
        dst[(size_t)(n0 + ty + i) * HS_ + k0 + tx] = __float2bfloat16(tile[tx][ty + i]);
}

// ---------------------------------------------------------------------------
// fused_norm_v: Q norm_rope + K norm_rope + V transpose in one launch.
__device__ __forceinline__ void norm_rope_row(const float* __restrict__ X,
                                              __hip_bfloat16* __restrict__ Y,
                                              const float* __restrict__ w,
                                              int row, int lane,
                                              int log2nh, int in_stride, float oscale) {
    int m = row >> log2nh;
    int head = row & ((1 << log2nh) - 1);
    int pos = m & (L_ - 1);
    const float* x = X + (size_t)m * in_stride + head * HD_;
    float x1 = x[lane], x2 = x[lane + 64];
    float ss = x1 * x1 + x2 * x2;
#pragma unroll
    for (int mm = 1; mm < 64; mm <<= 1) ss += __shfl_xor(ss, mm);
    float rms = rsqrtf(ss * (1.0f / 128.0f) + EPS_);
    float xn1 = x1 * rms * w[lane];
    float xn2 = x2 * rms * w[lane + 64];
    float inv_freq = __builtin_exp2f(-(float)lane * 0.20762050593046014f);
    float ang = (float)pos * inv_freq;
    float c = cosf(ang), s = sinf(ang);
    __hip_bfloat16* y = Y + (size_t)row * HD_;
    y[lane]      = __float2bfloat16((xn1 * c - xn2 * s) * oscale);
    y[lane + 64] = __float2bfloat16((xn2 * c + xn1 * s) * oscale);
}

__global__ __launch_bounds__(256) void fused_norm_v(
    const float* __restrict__ q_f32, __hip_bfloat16* __restrict__ q_bf,
    const float* __restrict__ kv_f32, __hip_bfloat16* __restrict__ k_bf,
    __hip_bfloat16* __restrict__ vt_bf,
    const float* __restrict__ qw, const float* __restrict__ kw) {
    __shared__ float tile[32][33];
    int bid = blockIdx.x;
    int lane = threadIdx.x & 63;
    if (bid < 16384) {
        int row = bid * 4 + (threadIdx.x >> 6);
        norm_rope_row(q_f32, q_bf, qw, row, lane, 4, 2048, SCALE_ * LOG2E_);
        return;
    }
    if (bid < 20480) {
        int row = (bid - 16384) * 4 + (threadIdx.x >> 6);
        norm_rope_row(kv_f32, k_bf, kw, row, lane, 2, 1024, 1.0f);
        return;
    }
    int vbid = bid - 20480;
    int xb = vbid & 63, yb = (vbid >> 6) & 3, zb = vbid >> 8;
    int b = zb >> 2, kv = zb & 3;
    int l0 = xb * 32, d0 = yb * 32;
    int tx = threadIdx.x & 31, ty = threadIdx.x >> 5;
#pragma unroll
    for (int i = 0; i < 32; i += 8)
        tile[ty + i][tx] = kv_f32[(size_t)(b * L_ + l0 + ty + i) * 1024 + 512 + kv * HD_ + d0 + tx];
    __syncthreads();
#pragma unroll
    for (int i = 0; i < 32; i += 8)
        vt_bf[((size_t)(b * NKV_ + kv) * HD_ + d0 + ty + i) * L_ + l0 + tx] =
            __float2bfloat16(tile[tx][ty + i]);
}

// ---------------------------------------------------------------------------
// 256x256 8-phase GEMM (unchanged, verified). K=2048.
#define GNT 32
#define GKB 4096   // K=2048 * 2B row stride
__global__ __launch_bounds__(512, 2) void gemm8_bf16(const __hip_bfloat16* __restrict__ A,
                                                     const __hip_bfloat16* __restrict__ Bt,
                                                     float* __restrict__ C1,
                                                     float* __restrict__ C2,
                                                     int Ntot, int splitN) {
    __shared__ __align__(16) char lds[131072];
    int t = threadIdx.x;
    int w = t >> 6, lane = t & 63;
    int row16 = lane & 15, quad = lane >> 4, e7 = row16 & 7;
    int wr = w >> 2, wc = w & 3;

    int gx = gridDim.x;
    int nwg = gx * gridDim.y;
    int bid = blockIdx.y * gx + blockIdx.x;
    int cpx = nwg >> 3;
    int swz = (bid & 7) * cpx + (bid >> 3);
    int bx = swz % gx, by = swz / gx;
    int m0 = bx * 256, n0 = by * 256;

    const char* baseA[2];
    const char* baseB[2];
#pragma unroll
    for (int kc = 0; kc < 2; ++kc) {
        int so = ((kc * 4 + quad) ^ e7) << 4;
        baseA[kc] = lds + wr * 16384 + row16 * 128 + so;
        baseB[kc] = lds + 65536 + wc * 8192 + row16 * 128 + so;
    }

    int r8 = lane >> 3;
    int sl = (lane & 7) ^ r8;
    char* dstA = lds + wr * 16384 + (w & 3) * 2048 + lane * 16;
    char* dstB = lds + 65536 + (w >> 1) * 8192 + (w & 1) * 2048 + lane * 16;
    const char* gA = (const char*)A +
        (size_t)(m0 + wr * 128 + (w & 3) * 16 + r8) * GKB + sl * 16;
    const char* gB = (const char*)Bt +
        (size_t)(n0 + (w >> 1) * 64 + (w & 1) * 16 + r8) * GKB + sl * 16;

    f32x4 acc[8][4] = {};
    bf16x8 a[4][2], b[2][2];

#pragma unroll
    for (int i = 0; i < 2; ++i) async_copy16(dstA + i * 1024, gA + i * 32768);
#pragma unroll
    for (int i = 0; i < 2; ++i) async_copy16(dstB + i * 1024, gB + i * 32768);
#pragma unroll
    for (int i = 0; i < 2; ++i) async_copy16(dstB + 4096 + i * 1024, gB + 131072 + i * 32768);
#pragma unroll
    for (int i = 0; i < 2; ++i) async_copy16(dstA + 8192 + i * 1024, gA + 262144 + i * 32768);

    for (int Tb = 0; Tb < GNT; Tb += 2) {
#pragma unroll
        for (int u = 0; u < 2; ++u) {
            const int T = Tb + u;
            const int cu = u * 32768, du = (u ^ 1) * 32768;
            const int tn = (T + 1 < GNT ? T + 1 : T) * 128;

            asm volatile("s_waitcnt vmcnt(4)" ::: "memory");
            __builtin_amdgcn_s_barrier();
            __builtin_amdgcn_sched_barrier(0);
#pragma unroll
            for (int mi = 0; mi < 4; ++mi)
#pragma unroll
                for (int kc = 0; kc < 2; ++kc)
                    a[mi][kc] = *(const bf16x8*)(baseA[kc] + cu + mi * 2048);
#pragma unroll
            for (int ni = 0; ni < 2; ++ni)
#pragma unroll
                for (int kc = 0; kc < 2; ++kc)
                    b[ni][kc] = *(const bf16x8*)(baseB[kc] + cu + ni * 2048);
#pragma unroll
            for (int i = 0; i < 2; ++i)
                async_copy16(dstA + du + i * 1024, gA + tn + i * 32768);
            asm volatile("s_waitcnt lgkmcnt(0)" ::: "memory");
            __builtin_amdgcn_sched_barrier(0);
            __builtin_amdgcn_s_setprio(1);
#pragma unroll
            for (int mi = 0; mi < 4; ++mi)
#pragma unroll
                for (int ni = 0; ni < 2; ++ni)
#pragma unroll
                    for (int kc = 0; kc < 2; ++kc)
                        acc[mi][ni] = mfma16(a[mi][kc], b[ni][kc], acc[mi][ni]);
            __builtin_amdgcn_s_setprio(0);

            asm volatile("s_waitcnt vmcnt(4)" ::: "memory");
            __builtin_amdgcn_s_barrier();
            __builtin_amdgcn_sched_barrier(0);
#pragma unroll
            for (int ni = 0; ni < 2; ++ni)
#pragma unroll
                for (int kc = 0; kc < 2; ++kc)
                    b[ni][kc] = *(const bf16x8*)(baseB[kc] + cu + 4096 + ni * 2048);
#pragma unroll
            for (int i = 0; i < 2; ++i)
                async_copy16(dstB + du + i * 1024, gB + tn + i * 32768);
            asm volatile("s_waitcnt lgkmcnt(0)" ::: "memory");
            __builtin_amdgcn_sched_barrier(0);
            __builtin_amdgcn_s_setprio(1);
#pragma unroll
            for (int mi = 0; mi < 4; ++mi)
#pragma unroll
                for (int ni = 0; ni < 2; ++ni)
#pragma unroll
                    for (int kc = 0; kc < 2; ++kc)
                        acc[mi][2 + ni] = mfma16(a[mi][kc], b[ni][kc], acc[mi][2 + ni]);
            __builtin_amdgcn_s_setprio(0);

            asm volatile("s_waitcnt vmcnt(4)" ::: "memory");
            __builtin_amdgcn_s_barrier();
            __builtin_amdgcn_sched_barrier(0);
#pragma unroll
            for (int mi = 0; mi < 4; ++mi)
#pragma unroll
                for (int kc = 0; kc < 2; ++kc)
                    a[mi][kc] = *(const bf16x8*)(baseA[kc] + cu + 8192 + mi * 2048);
#pragma unroll
            for (int i = 0; i < 2; ++i)
                async_copy16(dstB + du + 4096 + i * 1024, gB + 131072 + tn + i * 32768);
            asm volatile("s_waitcnt lgkmcnt(0)" ::: "memory");
            __builtin_amdgcn_sched_barrier(0);
            __builtin_amdgcn_s_setprio(1);
#pragma unroll
            for (int mi = 0; mi < 4; ++mi)
#pragma unroll
                for (int ni = 0; ni < 2; ++ni)
#pragma unroll
                    for (int kc = 0; kc < 2; ++kc)
                        acc[4 + mi][2 + ni] = mfma16(a[mi][kc], b[ni][kc], acc[4 + mi][2 + ni]);
            __builtin_amdgcn_s_setprio(0);

            __builtin_amdgcn_s_barrier();
            __builtin_amdgcn_sched_barrier(0);
#pragma unroll
            for (int ni = 0; ni < 2; ++ni)
#pragma unroll
                for (int kc = 0; kc < 2; ++kc)
                    b[ni][kc] = *(const bf16x8*)(baseB[kc] + cu + ni * 2048);
#pragma unroll
            for (int i = 0; i < 2; ++i)
                async_copy16(dstA + du + 8192 + i * 1024, gA + 262144 + tn + i * 32768);
            asm volatile("s_waitcnt lgkmcnt(0)" ::: "memory");
            __builtin_amdgcn_sched_barrier(0);
            __builtin_amdgcn_s_setprio(1);
#pragma unroll
            for (int mi = 0; mi < 4; ++mi)
#pragma unroll
                for (int ni = 0; ni < 2; ++ni)
#pragma unroll
                    for (int kc = 0; kc < 2; ++kc)
                        acc[4 + mi][ni] = mfma16(a[mi][kc], b[ni][kc], acc[4 + mi][ni]);
            __builtin_amdgcn_s_setprio(0);
        }
    }

    float* Cb; int cs, ccol0;
    if (n0 < splitN) { Cb = C1; cs = splitN; ccol0 = n0; }
    else             { Cb = C2; cs = Ntot - splitN; ccol0 = n0 - splitN; }
#pragma unroll
    for (int mi = 0; mi < 8; ++mi)
#pragma unroll
        for (int ni = 0; ni < 4; ++ni) {
            int rbase = m0 + wr * 128 + mi * 16 + quad * 4;
            int col = ccol0 + wc * 64 + ni * 16 + row16;
#pragma unroll
            for (int r = 0; r < 4; ++r)
                Cb[(size_t)(rbase + r) * cs + col] = acc[mi][ni][r];
        }
}

// ---------------------------------------------------------------------------
// 128x256-tile pipelined GEMM for the O-projection (unchanged, verified).
__global__ __launch_bounds__(512, 2) void gemm_o(const __hip_bfloat16* __restrict__ A,
                                                 const __hip_bfloat16* __restrict__ Bt,
                                                 float* __restrict__ C) {
    __shared__ __align__(16) char lds[98304];
    int t = threadIdx.x;
    int w = t >> 6, lane = t & 63;
    int row16 = lane & 15, quad = lane >> 4, e7 = row16 & 15 & 7;
    int wr = w >> 2, wc = w & 3;

    int gx = gridDim.x;
    int nwg = gx * gridDim.y;
    int bid = blockIdx.y * gx + blockIdx.x;
    int cpx = nwg >> 3;
    int swz = (bid & 7) * cpx + (bid >> 3);
    int bx = swz % gx, by = swz / gx;
    int m0 = bx * 128, n0 = by * 256;

    const char* baseA[2];
    const char* baseB[2];
#pragma unroll
    for (int kc = 0; kc < 2; ++kc) {
        int so = ((kc * 4 + quad) ^ e7) << 4;
        baseA[kc] = lds + wr * 8192 + row16 * 128 + so;
        baseB[kc] = lds + 32768 + wc * 8192 + row16 * 128 + so;
    }

    int r8 = lane >> 3;
    int sl = (lane & 7) ^ r8;
    int arow_lo = ((w & 4) << 4) + (w & 3) * 8;
    int li0 = w * 2;
    int brow_lo0 = ((li0) >> 2) * 64 + ((li0) & 3) * 8;
    int brow_lo1 = ((li0 + 1) >> 2) * 64 + ((li0 + 1) & 3) * 8;

    char* dAlo = lds + arow_lo * 128 + lane * 16;
    char* dBlo0 = lds + 32768 + brow_lo0 * 128 + lane * 16;
    char* dBlo1 = lds + 32768 + brow_lo1 * 128 + lane * 16;
    const char* gAlo = (const char*)A + (size_t)(m0 + arow_lo + r8) * GKB + sl * 16;
    const char* gBlo0 = (const char*)Bt + (size_t)(n0 + brow_lo0 + r8) * GKB + sl * 16;
    const char* gBlo1 = (const char*)Bt + (size_t)(n0 + brow_lo1 + r8) * GKB + sl * 16;
    const int HI_L = 32 * 128;
    const size_t HI_G = (size_t)32 * GKB;

    f32x4 acc[4][4] = {};
    bf16x8 a[2][2], b[2][2];

    async_copy16(dAlo, gAlo);
    async_copy16(dBlo0, gBlo0);
    async_copy16(dBlo1, gBlo1);
    async_copy16(dBlo0 + HI_L, gBlo0 + HI_G);
    async_copy16(dBlo1 + HI_L, gBlo1 + HI_G);
    async_copy16(dAlo + HI_L, gAlo + HI_G);

    for (int Tb = 0; Tb < GNT; Tb += 2) {
#pragma unroll
        for (int u = 0; u < 2; ++u) {
            const int T = Tb + u;
            const int cuA = u * 16384, duA = (u ^ 1) * 16384;
            const int cuB = u * 32768, duB = (u ^ 1) * 32768;
            const int tn = (T + 1 < GNT ? T + 1 : T) * 128;

            asm volatile("s_waitcnt vmcnt(3)" ::: "memory");
            __builtin_amdgcn_s_barrier();
            __builtin_amdgcn_sched_barrier(0);
#pragma unroll
            for (int mi = 0; mi < 2; ++mi)
#pragma unroll
                for (int kc = 0; kc < 2; ++kc)
                    a[mi][kc] = *(const bf16x8*)(baseA[kc] + cuA + mi * 2048);
#pragma unroll
            for (int ni = 0; ni < 2; ++ni)
#pragma unroll
                for (int kc = 0; kc < 2; ++kc)
                    b[ni][kc] = *(const bf16x8*)(baseB[kc] + cuB + ni * 2048);
            async_copy16(dAlo + duA, gAlo + tn);
            asm volatile("s_waitcnt lgkmcnt(0)" ::: "memory");
            __builtin_amdgcn_sched_barrier(0);
            __builtin_amdgcn_s_setprio(1);
#pragma unroll
            for (int mi = 0; mi < 2; ++mi)
#pragma unroll
                for (int ni = 0; ni < 2; ++ni)
#pragma unroll
                    for (int kc = 0; kc < 2; ++kc)
                        acc[mi][ni] = mfma16(a[mi][kc], b[ni][kc], acc[mi][ni]);
            __builtin_amdgcn_s_setprio(0);

            asm volatile("s_waitcnt vmcnt(2)" ::: "memory");
            __builtin_amdgcn_s_barrier();
            __builtin_amdgcn_sched_barrier(0);
#pragma unroll
            for (int ni = 0; ni < 2; ++ni)
#pragma unroll
                for (int kc = 0; kc < 2; ++kc)
                    b[ni][kc] = *(const bf16x8*)(baseB[kc] + cuB + 4096 + ni * 2048);
            async_copy16(dBlo0 + duB, gBlo0 + tn);
            async_copy16(dBlo1 + duB, gBlo1 + tn);
            asm volatile("s_waitcnt lgkmcnt(0)" ::: "memory");
            __builtin_amdgcn_sched_barrier(0);
            __builtin_amdgcn_s_setprio(1);
#pragma unroll
            for (int mi = 0; mi < 2; ++mi)
#pragma unroll
                for (int ni = 0; ni < 2; ++ni)
#pragma unroll
                    for (int kc = 0; kc < 2; ++kc)
                        acc[mi][2 + ni] = mfma16(a[mi][kc], b[ni][kc], acc[mi][2 + ni]);
            __builtin_amdgcn_s_setprio(0);

            asm volatile("s_waitcnt vmcnt(3)" ::: "memory");
            __builtin_amdgcn_s_barrier();
            __builtin_amdgcn_sched_barrier(0);
#pragma unroll
            for (int mi = 0; mi < 2; ++mi)
#pragma unroll
                for (int kc = 0; kc < 2; ++kc)
                    a[mi][kc] = *(const bf16x8*)(baseA[kc] + cuA + 4096 + mi * 2048);
            async_copy16(dBlo0 + HI_L + duB, gBlo0 + HI_G + tn);
            async_copy16(dBlo1 + HI_L + duB, gBlo1 + HI_G + tn);
            asm volatile("s_waitcnt lgkmcnt(0)" ::: "memory");
            __builtin_amdgcn_sched_barrier(0);
            __builtin_amdgcn_s_setprio(1);
#pragma unroll
            for (int mi = 0; mi < 2; ++mi)
#pragma unroll
                for (int ni = 0; ni < 2; ++ni)
#pragma unroll
                    for (int kc = 0; kc < 2; ++kc)
                        acc[2 + mi][2 + ni] = mfma16(a[mi][kc], b[ni][kc], acc[2 + mi][2 + ni]);
            __builtin_amdgcn_s_setprio(0);

            __builtin_amdgcn_s_barrier();
            __builtin_amdgcn_sched_barrier(0);
#pragma unroll
            for (int ni = 0; ni < 2; ++ni)
#pragma unroll
                for (int kc = 0; kc < 2; ++kc)
                    b[ni][kc] = *(const bf16x8*)(baseB[kc] + cuB + ni * 2048);
            async_copy16(dAlo + HI_L + duA, gAlo + HI_G + tn);
            asm volatile("s_waitcnt lgkmcnt(0)" ::: "memory");
            __builtin_amdgcn_sched_barrier(0);
            __builtin_amdgcn_s_setprio(1);
#pragma unroll
            for (int mi = 0; mi < 2; ++mi)
#pragma unroll
                for (int ni = 0; ni < 2; ++ni)
#pragma unroll
                    for (int kc = 0; kc < 2; ++kc)
                        acc[2 + mi][ni] = mfma16(a[mi][kc], b[ni][kc], acc[2 + mi][ni]);
            __builtin_amdgcn_s_setprio(0);
        }
    }
    asm volatile("s_waitcnt vmcnt(0)" ::: "memory");

#pragma unroll
    for (int mi = 0; mi < 4; ++mi)
#pragma unroll
        for (int ni = 0; ni < 4; ++ni) {
            int rbase = m0 + wr * 64 + mi * 16 + quad * 4;
            int col = n0 + wc * 64 + ni * 16 + row16;
#pragma unroll
            for (int r = 0; r < 4; ++r)
                C[(size_t)(rbase + r) * 2048 + col] = acc[mi][ni][r];
        }
}

// ---------------------------------------------------------------------------
// Flash attention v10: 2 waves x 32 q-rows, KVBLK=32, single pass per block.
// - K/V fragment reuse across two 16-row q-groups (v9's verified math):
//   18 LDS b128-reads per 32 MFMAs vs v8's 34 -> LDS traffic/work halved.
// - LDS 35.1 KiB (sK 2x8K, sV 2x8K, sP stride-40) -> 4 blocks/CU ->
//   8 waves/CU (v8's occupancy, which v9 lost at 1 block of 128 thr).
// - 1024 blocks (32 qt x 16 h x 2 b), all co-resident (256 CU x 4).
//   Causal imbalance (steps = 2*qt+2) balanced by interleaving
//   qt = u&1 ? 31-(u>>1) : u>>1 across consecutive block ids.
__global__ __launch_bounds__(128, 2) void flash_attn(const __hip_bfloat16* __restrict__ Q,
                                                     const __hip_bfloat16* __restrict__ Kb,
                                                     const __hip_bfloat16* __restrict__ Vt,
                                                     __hip_bfloat16* __restrict__ O) {
    __shared__ __align__(16) __hip_bfloat16 sK[2][32 * 128];   // [key][dim], swizzled
    __shared__ __align__(16) __hip_bfloat16 sV[2][128 * 32];   // [dim][key], swizzled
    __shared__ __align__(16) __hip_bfloat16 sP[2][16 * 40];    // per-wave P, stride 40

    int t = threadIdx.x, wave = t >> 6, lane = t & 63;
    int row16 = lane & 15, quad = lane >> 4;
    int h = blockIdx.y, b = blockIdx.z;
    int kv = h & (NKV_ - 1);
    int u = blockIdx.x;                       // 0..31
    int qt = (u & 1) ? 31 - (u >> 1) : (u >> 1);
    int nSteps = 2 * qt + 2;

    int e7 = row16 & 7;
    int kOff[4];
#pragma unroll
    for (int kc = 0; kc < 4; ++kc)
        kOff[kc] = row16 * 256 + (((kc * 4 + quad) ^ e7) * 16);
    int vOff = row16 * 64 + ((quad ^ (row16 & 3)) * 16);

    const char* sKb = (const char*)&sK[0][0];
    const char* sVb = (const char*)&sV[0][0];
    char* myP = (char*)&sP[wave][0];
    int pW = row16 * 80 + quad * 8;
    int pR = row16 * 80 + quad * 16;

    // staging: 128 lanes cover the 32x128 K tile (4 copies) and 128x32 V tile (4)
    const char* gK[4];
    const char* gV[4];
#pragma unroll
    for (int i = 0; i < 4; ++i) {
        int rk = i * 8 + (lane >> 4);                 // K row 0..31 (t>=64 repeats rows: no—
        // lane is 0..63 per wave; with 2 waves t>>4 spans 0..7: use thread id
        rk = i * 8 + (t >> 4);                        // K row 0..31 across 128 threads
        int ck = (t & 15) ^ (rk & 7);
        gK[i] = (const char*)(Kb + ((size_t)(b * L_ + rk) * NKV_ + kv) * HD_ + ck * 8);
        int rv = i * 32 + (t >> 2);                   // V row (dim) 0..127
        int cv = (t & 3) ^ (rv & 3);
        gV[i] = (const char*)(Vt + ((size_t)(b * NKV_ + kv) * HD_ + rv) * L_ + cv * 8);
    }
    char* dK = (char*)&sK[0][0] + t * 16;
    char* dV = (char*)&sV[0][0] + t * 16;

    int q0w = qt * 64 + wave * 32;

    bf16x8 qf[2][4];
    f32x4 accO[2][8];
    float lrow[2];
#pragma unroll
    for (int qg = 0; qg < 2; ++qg) {
        const __hip_bfloat16* qbase =
            Q + ((size_t)(b * L_ + q0w + qg * 16 + row16) * NH_ + h) * HD_ + quad * 8;
#pragma unroll
        for (int kc = 0; kc < 4; ++kc) qf[qg][kc] = *(const bf16x8*)(qbase + kc * 32);
#pragma unroll
        for (int db = 0; db < 8; ++db) accO[qg][db] = f32x4{0.f, 0.f, 0.f, 0.f};
        lrow[qg] = 0.f;
    }

    auto stage = [&](int s1) {
        int buf = (s1 & 1) * 8192;
        int ko = s1 * 32768;                   // 32 keys * 1024 B/key-row
        int vo = s1 * 64;                      // 32 keys * 2 B along L
#pragma unroll
        for (int i = 0; i < 4; ++i) {
            async_copy16(dK + buf + i * 2048, gK[i] + ko);
            async_copy16(dV + buf + i * 2048, gV[i] + vo);
        }
    };

    stage(0);
    for (int s = 0; s < nSteps; ++s) {
        __syncthreads();                  // staging s visible; compute s-1 done
        if (s + 1 < nSteps) stage(s + 1);
        int kcur = s * 32;
        const char* cK = sKb + (s & 1) * 8192;
        const char* cV = sVb + (s & 1) * 8192;

        // ---- S^T = K Q^T for both q-groups; each kf read feeds 2 MFMAs
        f32x4 st[2][2];
        __builtin_amdgcn_s_setprio(1);
#pragma unroll
        for (int kb = 0; kb < 2; ++kb) {
            bf16x8 kf[4];
#pragma unroll
            for (int kc = 0; kc < 4; ++kc)
                kf[kc] = *(const bf16x8*)(cK + kb * 4096 + kOff[kc]);
#pragma unroll
            for (int qg = 0; qg < 2; ++qg) {
                f32x4 acc = {};
#pragma unroll
                for (int kc = 0; kc < 4; ++kc)
                    acc = mfma16(kf[kc], qf[qg][kc], acc);
                st[qg][kb] = acc;
            }
        }
        __builtin_amdgcn_s_setprio(0);

        // ---- no-max softmax per group
        float p[2][2][4];
        if (kcur + 31 > q0w) {            // diagonal region for this wave
#pragma unroll
            for (int qg = 0; qg < 2; ++qg) {
                int qgRel = q0w + qg * 16 + row16 - kcur - quad * 4;
#pragma unroll
                for (int kb = 0; kb < 2; ++kb)
#pragma unroll
                    for (int r = 0; r < 4; ++r) {
                        float e = __builtin_exp2f(st[qg][kb][r]);
                        p[qg][kb][r] = (kb * 16 + r <= qgRel) ? e : 0.f;
                    }
            }
        } else {
#pragma unroll
            for (int qg = 0; qg < 2; ++qg)
#pragma unroll
                for (int kb = 0; kb < 2; ++kb)
#pragma unroll
                    for (int r = 0; r < 4; ++r)
                        p[qg][kb][r] = __builtin_exp2f(st[qg][kb][r]);
        }
#pragma unroll
        for (int qg = 0; qg < 2; ++qg)
#pragma unroll
            for (int kb = 0; kb < 2; ++kb)
#pragma unroll
                for (int r = 0; r < 4; ++r) lrow[qg] += p[qg][kb][r];

        // ---- P0 -> sP -> pf0; P1 -> sP (same slots) -> pf1 (wave-ordered DS)
        bf16x8 pf0, pf1;
#pragma unroll
        for (int kb = 0; kb < 2; ++kb) {
            uint2 uu;
            uu.x = cvtpk(p[0][kb][0], p[0][kb][1]);
            uu.y = cvtpk(p[0][kb][2], p[0][kb][3]);
            *(uint2*)(myP + pW + kb * 32) = uu;
        }
        asm volatile("s_waitcnt lgkmcnt(0)" ::: "memory");
        pf0 = *(const bf16x8*)(myP + pR);
#pragma unroll
        for (int kb = 0; kb < 2; ++kb) {
            uint2 uu;
            uu.x = cvtpk(p[1][kb][0], p[1][kb][1]);
            uu.y = cvtpk(p[1][kb][2], p[1][kb][3]);
            *(uint2*)(myP + pW + kb * 32) = uu;
        }
        asm volatile("s_waitcnt lgkmcnt(0)" ::: "memory");
        pf1 = *(const bf16x8*)(myP + pR);

        // ---- O^T += V^T P^T; each vf read feeds 2 MFMAs
        __builtin_amdgcn_s_setprio(1);
#pragma unroll
        for (int db = 0; db < 8; ++db) {
            bf16x8 vf = *(const bf16x8*)(cV + db * 1024 + vOff);
            accO[0][db] = mfma16(vf, pf0, accO[0][db]);
            accO[1][db] = mfma16(vf, pf1, accO[1][db]);
        }
        __builtin_amdgcn_s_setprio(0);
    }

    // epilogue
#pragma unroll
    for (int qg = 0; qg < 2; ++qg) {
        float l = lrow[qg];
        l += __shfl_xor(l, 16);
        l += __shfl_xor(l, 32);
        float linv = 1.0f / l;
        __hip_bfloat16* obase =
            O + ((size_t)(b * L_ + q0w + qg * 16 + row16) * NH_ + h) * HD_;
#pragma unroll
        for (int db = 0; db < 8; ++db) {
            union { __hip_bfloat16 h4[4]; short4 s4; } uo;
#pragma unroll
            for (int r = 0; r < 4; ++r) uo.h4[r] = __float2bfloat16(accO[qg][db][r] * linv);
            *(short4*)(obase + db * 16 + quad * 4) = uo.s4;
        }
    }
}

// ---------------------------------------------------------------------------
extern "C" void kernel_launch(void* const* d_in, const int* in_sizes, int n_in,
                              void* d_out, int out_size, void* d_ws, size_t ws_size,
                              hipStream_t stream) {
    const float* hidden = (const float*)d_in[0];
    const float* Wq = (const float*)d_in[1];
    const float* Wk = (const float*)d_in[2];
    const float* Wv = (const float*)d_in[3];
    const float* Wo = (const float*)d_in[4];
    const float* qw = (const float*)d_in[5];
    const float* kw = (const float*)d_in[6];
    float* out = (float*)d_out;

    char* ws = (char*)d_ws;
    size_t off = 0;
    auto alloc = [&](size_t bytes) { char* p = ws + off; off += (bytes + 255) & ~255ull; return p; };
    __hip_bfloat16* Wq_t = (__hip_bfloat16*)alloc((size_t)HS_ * NH_ * HD_ * 2);   // 8 MB
    __hip_bfloat16* Wk_t = (__hip_bfloat16*)alloc((size_t)HS_ * NKV_ * HD_ * 2);  // 2 MB (contiguous after Wq_t)
    __hip_bfloat16* Wv_t = (__hip_bfloat16*)alloc((size_t)HS_ * NKV_ * HD_ * 2);  // 2 MB (contiguous after Wk_t)
    __hip_bfloat16* Wo_t = (__hip_bfloat16*)alloc((size_t)HS_ * NH_ * HD_ * 2);   // 8 MB
    __hip_bfloat16* A_h  = (__hip_bfloat16*)alloc((size_t)B_ * L_ * HS_ * 2);     // 16 MB; reused as attn_bf
    float* kv_f32 = (float*)alloc((size_t)B_ * L_ * 1024 * 4);                    // 16 MB [M,1024] = K|V
    __hip_bfloat16* q_bf  = (__hip_bfloat16*)alloc((size_t)B_ * L_ * NH_ * HD_ * 2);
    __hip_bfloat16* k_bf  = (__hip_bfloat16*)alloc((size_t)B_ * L_ * NKV_ * HD_ * 2);
    __hip_bfloat16* vt_bf = (__hip_bfloat16*)alloc((size_t)B_ * NKV_ * HD_ * L_ * 2);
    float* q_f32 = out;                     // reuse d_out as pre-norm Q scratch
    __hip_bfloat16* attn_bf = A_h;

    const int M = B_ * L_;

    // 1) hidden cvt + all 4 weight transposes in one launch
    fused_prep<<<18432, 256, 0, stream>>>(hidden, A_h, Wq, Wq_t, Wk, Wk_t, Wv, Wv_t, Wo, Wo_t);
    // 2) fused QKV projection
    gemm8_bf16<<<dim3(M / 256, 3072 / 256), 512, 0, stream>>>(
        A_h, Wq_t, q_f32, kv_f32, 3072, 2048);
    // 3) Q-norm-rope + K-norm-rope + V transpose in one launch
    fused_norm_v<<<22528, 256, 0, stream>>>(q_f32, q_bf, kv_f32, k_bf, vt_bf, qw, kw);
    // 4) attention (v10: 1024 blocks of 128 threads)
    flash_attn<<<dim3(32, NH_, B_), 128, 0, stream>>>(q_bf, k_bf, vt_bf, attn_bf);
    // 5) O projection
    gemm_o<<<dim3(M / 128, 2048 / 256), 512, 0, stream>>>(attn_bf, Wo_t, out);
}